// Round 5
// baseline (458.001 us; speedup 1.0000x reference)
//
#include <hip/hip_runtime.h>

#define BN_EPS 1e-5f

typedef __attribute__((ext_vector_type(8))) __bf16 bf16x8;
typedef __attribute__((ext_vector_type(4))) float f32x4;

__device__ __forceinline__ unsigned short f2bf(float f) {
    unsigned int u = __float_as_uint(f);
    u = (u + 0x7fffu + ((u >> 16) & 1u)) >> 16;
    return (unsigned short)u;
}
__device__ __forceinline__ float bfLo(unsigned int w) { return __uint_as_float(w << 16); }
__device__ __forceinline__ float bfHi(unsigned int w) { return __uint_as_float(w & 0xffff0000u); }

// ================= CSR construction (+ degree-bucket permutation) =================

__global__ void hist_kernel(const int* __restrict__ dst, int* __restrict__ deg, int E) {
    int e = blockIdx.x * blockDim.x + threadIdx.x;
    if (e < E) atomicAdd(&deg[dst[e]], 1);
}

// per-256-chunk inclusive scan of deg; chunk totals to bsum; ALSO 64-bucket degree histogram
__global__ void scan_block(const int* __restrict__ deg, int* __restrict__ incl,
                           int* __restrict__ bsum, int* __restrict__ bhist, int N) {
    __shared__ int s[256];
    __shared__ int bh[64];
    int i = blockIdx.x * 256 + threadIdx.x;
    int v = (i < N) ? deg[i] : 0;
    s[threadIdx.x] = v;
    if (threadIdx.x < 64) bh[threadIdx.x] = 0;
    __syncthreads();
    if (i < N) atomicAdd(&bh[v < 63 ? v : 63], 1);
#pragma unroll
    for (int off = 1; off < 256; off <<= 1) {
        int t = (threadIdx.x >= off) ? s[threadIdx.x - off] : 0;
        __syncthreads();
        s[threadIdx.x] += t;
        __syncthreads();
    }
    if (i < N) incl[i] = s[threadIdx.x];
    if (threadIdx.x == 255) bsum[blockIdx.x] = s[255];
    if (threadIdx.x < 64 && bh[threadIdx.x] > 0) atomicAdd(&bhist[threadIdx.x], bh[threadIdx.x]);
}

// single-block: exclusive scan of chunk totals (nb <= 256) AND 64-bucket exclusive scan -> bpos
__global__ void scan_top(int* __restrict__ bsum, int nb,
                         const int* __restrict__ bhist, int* __restrict__ bpos) {
    __shared__ int s[256];
    int v = (threadIdx.x < nb) ? bsum[threadIdx.x] : 0;
    s[threadIdx.x] = v;
    __syncthreads();
#pragma unroll
    for (int off = 1; off < 256; off <<= 1) {
        int t = (threadIdx.x >= off) ? s[threadIdx.x - off] : 0;
        __syncthreads();
        s[threadIdx.x] += t;
        __syncthreads();
    }
    if (threadIdx.x < nb) bsum[threadIdx.x] = s[threadIdx.x] - v;
    if (threadIdx.x < 64) {
        int bv = bhist[threadIdx.x];
        int inc = bv;
#pragma unroll
        for (int off = 1; off < 64; off <<= 1) {
            int t = __shfl_up(inc, off);
            if ((threadIdx.x & 63) >= off) inc += t;
        }
        bpos[threadIdx.x] = inc - bv;
    }
}

// rowptr/pos from scans; ALSO scatter node into degree-sorted perm
__global__ void finalize_rowptr(const int* __restrict__ deg, const int* __restrict__ incl,
                                const int* __restrict__ boff, int* __restrict__ rowptr,
                                int* __restrict__ pos, int* __restrict__ bpos,
                                int* __restrict__ perm, int N, int E) {
    int i = blockIdx.x * 256 + threadIdx.x;
    if (i < N) {
        int d = deg[i];
        int r = incl[i] - d + boff[i >> 8];
        rowptr[i] = r;
        pos[i] = r;
        int slot = atomicAdd(&bpos[d < 63 ? d : 63], 1);
        perm[slot] = i;
    }
    if (i == 0) rowptr[N] = E;
}

__global__ void fill_kernel(const int* __restrict__ src, const int* __restrict__ dst,
                            int* __restrict__ pos, int* __restrict__ col, int E) {
    int e = blockIdx.x * blockDim.x + threadIdx.x;
    if (e < E) {
        int slot = atomicAdd(&pos[dst[e]], 1);
        col[slot] = src[e];
    }
}

// ============ one-time prep: x -> bf16 AND swizzle all 3 weights ============
// Wsw[((ct*4+q)*64 + l)*8 + j] = bf16( W[q*32 + (l>>4)*8 + j][ct*16 + (l&15)] )
__global__ void convert_and_prep(const float* __restrict__ x, unsigned short* __restrict__ hb,
                                 int total4,
                                 const float* __restrict__ W1, const float* __restrict__ W2,
                                 const float* __restrict__ W3,
                                 unsigned short* __restrict__ w1s, unsigned short* __restrict__ w2s,
                                 unsigned short* __restrict__ w3s) {
    int tid0 = blockIdx.x * blockDim.x + threadIdx.x;
    if (tid0 < 40960) {
        int idx = tid0;
        const float* W; unsigned short* O; int NOUT;
        if (idx < 16384)      { W = W1; O = w1s; NOUT = 128; }
        else if (idx < 32768) { W = W2; O = w2s; NOUT = 128; idx -= 16384; }
        else                  { W = W3; O = w3s; NOUT = 64;  idx -= 32768; }
        int j = idx & 7;
        int l = (idx >> 3) & 63;
        int q = (idx >> 9) & 3;
        int ct = idx >> 11;
        int k = q * 32 + ((l >> 4) & 3) * 8 + j;
        int c = ct * 16 + (l & 15);
        O[idx] = f2bf(W[(size_t)k * NOUT + c]);
    }
    int stride = gridDim.x * blockDim.x;
    for (int i = tid0; i < total4; i += stride) {
        float4 v = reinterpret_cast<const float4*>(x)[i];
        ushort4 o;
        o.x = f2bf(v.x); o.y = f2bf(v.y); o.z = f2bf(v.z); o.w = f2bf(v.w);
        reinterpret_cast<ushort4*>(hb)[i] = o;
    }
}

// ============ plain gather (layer 1): agg[i] = h[i] + sum_j h[j] ============
__global__ void gather_agg_bf(const unsigned short* __restrict__ h,
                              const int* __restrict__ rowptr, const int* __restrict__ col,
                              const int* __restrict__ perm,
                              unsigned short* __restrict__ agg, int N) {
    int t = blockIdx.x * blockDim.x + threadIdx.x;
    int ni = t >> 4;
    if (ni >= N) return;
    int node = perm[ni];
    int part = (t & 15) * 8;
    const int beg = rowptr[node], end = rowptr[node + 1];

    float acc[8];
    {
        uint4 sv = *reinterpret_cast<const uint4*>(h + (size_t)node * 128 + part);
        acc[0] = bfLo(sv.x); acc[1] = bfHi(sv.x);
        acc[2] = bfLo(sv.y); acc[3] = bfHi(sv.y);
        acc[4] = bfLo(sv.z); acc[5] = bfHi(sv.z);
        acc[6] = bfLo(sv.w); acc[7] = bfHi(sv.w);
    }
    int e = beg;
    for (; e + 1 < end; e += 2) {
        int s0 = col[e], s1 = col[e + 1];
        uint4 v0 = *reinterpret_cast<const uint4*>(h + (size_t)s0 * 128 + part);
        uint4 v1 = *reinterpret_cast<const uint4*>(h + (size_t)s1 * 128 + part);
        acc[0] += bfLo(v0.x) + bfLo(v1.x); acc[1] += bfHi(v0.x) + bfHi(v1.x);
        acc[2] += bfLo(v0.y) + bfLo(v1.y); acc[3] += bfHi(v0.y) + bfHi(v1.y);
        acc[4] += bfLo(v0.z) + bfLo(v1.z); acc[5] += bfHi(v0.z) + bfHi(v1.z);
        acc[6] += bfLo(v0.w) + bfLo(v1.w); acc[7] += bfHi(v0.w) + bfHi(v1.w);
    }
    if (e < end) {
        uint4 v0 = *reinterpret_cast<const uint4*>(h + (size_t)col[e] * 128 + part);
        acc[0] += bfLo(v0.x); acc[1] += bfHi(v0.x);
        acc[2] += bfLo(v0.y); acc[3] += bfHi(v0.y);
        acc[4] += bfLo(v0.z); acc[5] += bfHi(v0.z);
        acc[6] += bfLo(v0.w); acc[7] += bfHi(v0.w);
    }
    uint4 o;
    o.x = (unsigned int)f2bf(acc[0]) | ((unsigned int)f2bf(acc[1]) << 16);
    o.y = (unsigned int)f2bf(acc[2]) | ((unsigned int)f2bf(acc[3]) << 16);
    o.z = (unsigned int)f2bf(acc[4]) | ((unsigned int)f2bf(acc[5]) << 16);
    o.w = (unsigned int)f2bf(acc[6]) | ((unsigned int)f2bf(acc[7]) << 16);
    *reinterpret_cast<uint4*>(agg + (size_t)node * 128 + part) = o;
}

// ============ BN+ReLU-fused gather (layers 2,3) ============
// h := relu(raw*a + c) applied on the fly; agg[i] = h[i] + sum_j h[j]
__global__ void gather_bn_agg(const unsigned short* __restrict__ raw,
                              const float* __restrict__ sumsPad, const float* __restrict__ sqsPad,
                              const float* __restrict__ g, const float* __restrict__ be,
                              const int* __restrict__ rowptr, const int* __restrict__ col,
                              const int* __restrict__ perm,
                              unsigned short* __restrict__ agg, int N, float invN) {
    int t = blockIdx.x * blockDim.x + threadIdx.x;
    int ni = t >> 4;
    if (ni >= N) return;
    int node = perm[ni];
    int part = (t & 15) * 8;
    float a8[8], c8[8];
#pragma unroll
    for (int k = 0; k < 8; ++k) {
        int c = part + k;
        float m = sumsPad[c * 16] * invN;
        float v = sqsPad[c * 16] * invN - m * m;
        float ai = g[c] * rsqrtf(v + BN_EPS);
        a8[k] = ai;
        c8[k] = be[c] - m * ai;
    }
    const int beg = rowptr[node], end = rowptr[node + 1];
    float acc[8];
    {
        uint4 sv = *reinterpret_cast<const uint4*>(raw + (size_t)node * 128 + part);
        float e0 = bfLo(sv.x), e1 = bfHi(sv.x), e2 = bfLo(sv.y), e3 = bfHi(sv.y);
        float e4 = bfLo(sv.z), e5 = bfHi(sv.z), e6 = bfLo(sv.w), e7 = bfHi(sv.w);
        acc[0] = fmaxf(fmaf(e0, a8[0], c8[0]), 0.f);
        acc[1] = fmaxf(fmaf(e1, a8[1], c8[1]), 0.f);
        acc[2] = fmaxf(fmaf(e2, a8[2], c8[2]), 0.f);
        acc[3] = fmaxf(fmaf(e3, a8[3], c8[3]), 0.f);
        acc[4] = fmaxf(fmaf(e4, a8[4], c8[4]), 0.f);
        acc[5] = fmaxf(fmaf(e5, a8[5], c8[5]), 0.f);
        acc[6] = fmaxf(fmaf(e6, a8[6], c8[6]), 0.f);
        acc[7] = fmaxf(fmaf(e7, a8[7], c8[7]), 0.f);
    }
    for (int e = beg; e < end; ++e) {
        uint4 v0 = *reinterpret_cast<const uint4*>(raw + (size_t)col[e] * 128 + part);
        acc[0] += fmaxf(fmaf(bfLo(v0.x), a8[0], c8[0]), 0.f);
        acc[1] += fmaxf(fmaf(bfHi(v0.x), a8[1], c8[1]), 0.f);
        acc[2] += fmaxf(fmaf(bfLo(v0.y), a8[2], c8[2]), 0.f);
        acc[3] += fmaxf(fmaf(bfHi(v0.y), a8[3], c8[3]), 0.f);
        acc[4] += fmaxf(fmaf(bfLo(v0.z), a8[4], c8[4]), 0.f);
        acc[5] += fmaxf(fmaf(bfHi(v0.z), a8[5], c8[5]), 0.f);
        acc[6] += fmaxf(fmaf(bfLo(v0.w), a8[6], c8[6]), 0.f);
        acc[7] += fmaxf(fmaf(bfHi(v0.w), a8[7], c8[7]), 0.f);
    }
    uint4 o;
    o.x = (unsigned int)f2bf(acc[0]) | ((unsigned int)f2bf(acc[1]) << 16);
    o.y = (unsigned int)f2bf(acc[2]) | ((unsigned int)f2bf(acc[3]) << 16);
    o.z = (unsigned int)f2bf(acc[4]) | ((unsigned int)f2bf(acc[5]) << 16);
    o.w = (unsigned int)f2bf(acc[6]) | ((unsigned int)f2bf(acc[7]) << 16);
    *reinterpret_cast<uint4*>(agg + (size_t)node * 128 + part) = o;
}

// ========== MFMA GEMM (NOUT=128) + bias + fused column stats; bf16 raw out ==========
__global__ __launch_bounds__(256) void gemm128_stats(const unsigned short* __restrict__ A,
                                                     const unsigned short* __restrict__ Wsw,
                                                     const float* __restrict__ bias,
                                                     unsigned short* __restrict__ outb,
                                                     float* __restrict__ sumsPad,
                                                     float* __restrict__ sqsPad, int N) {
    __shared__ float red[2][4][128];
    const int lane = threadIdx.x & 63;
    const int w = threadIdx.x >> 6;
    const int r0 = blockIdx.x * 64 + w * 16;
    int arow = r0 + (lane & 15);
    if (arow >= N) arow = N - 1;
    const int kb = lane >> 4;
    const unsigned short* ap = A + (size_t)arow * 128 + kb * 8;

    bf16x8 a[4];
#pragma unroll
    for (int q = 0; q < 4; ++q) a[q] = *reinterpret_cast<const bf16x8*>(ap + q * 32);

    f32x4 acc[8];
#pragma unroll
    for (int ct = 0; ct < 8; ++ct) acc[ct] = (f32x4){0.f, 0.f, 0.f, 0.f};

    const bf16x8* wp = reinterpret_cast<const bf16x8*>(Wsw) + lane;
#pragma unroll
    for (int ct = 0; ct < 8; ++ct)
#pragma unroll
        for (int q = 0; q < 4; ++q)
            acc[ct] = __builtin_amdgcn_mfma_f32_16x16x32_bf16(a[q], wp[(ct * 4 + q) * 64],
                                                              acc[ct], 0, 0, 0);

    const int crow0 = r0 + (lane >> 4) * 4;
    const int ccol = lane & 15;
#pragma unroll
    for (int ct = 0; ct < 8; ++ct) {
        int c = ct * 16 + ccol;
        float bv = bias[c];
        float s = 0.f, qq = 0.f;
#pragma unroll
        for (int j = 0; j < 4; ++j) {
            int r = crow0 + j;
            if (r < N) {
                float o = acc[ct][j] + bv;
                outb[(size_t)r * 128 + c] = f2bf(o);
                s += o; qq += o * o;
            }
        }
        s += __shfl_xor(s, 16); s += __shfl_xor(s, 32);
        qq += __shfl_xor(qq, 16); qq += __shfl_xor(qq, 32);
        if (lane < 16) { red[0][w][c] = s; red[1][w][c] = qq; }
    }
    __syncthreads();
    int tid = threadIdx.x;
    if (tid < 128) {
        float S = red[0][0][tid] + red[0][1][tid] + red[0][2][tid] + red[0][3][tid];
        atomicAdd(&sumsPad[tid * 16], S);
    } else {
        int c = tid - 128;
        float Q = red[1][0][c] + red[1][1][c] + red[1][2][c] + red[1][3][c];
        atomicAdd(&sqsPad[c * 16], Q);
    }
}

// ========== MFMA GEMM (NOUT=64) + bias + fused log_softmax ==========
__global__ __launch_bounds__(256) void gemm64_lsm(const unsigned short* __restrict__ A,
                                                  const unsigned short* __restrict__ Wsw,
                                                  const float* __restrict__ bias,
                                                  float* __restrict__ out, int N) {
    const int lane = threadIdx.x & 63;
    const int w = threadIdx.x >> 6;
    const int r0 = blockIdx.x * 64 + w * 16;
    int arow = r0 + (lane & 15);
    if (arow >= N) arow = N - 1;
    const int kb = lane >> 4;
    const unsigned short* ap = A + (size_t)arow * 128 + kb * 8;

    bf16x8 a[4];
#pragma unroll
    for (int q = 0; q < 4; ++q) a[q] = *reinterpret_cast<const bf16x8*>(ap + q * 32);

    f32x4 acc[4];
#pragma unroll
    for (int ct = 0; ct < 4; ++ct) acc[ct] = (f32x4){0.f, 0.f, 0.f, 0.f};

    const bf16x8* wp = reinterpret_cast<const bf16x8*>(Wsw) + lane;
#pragma unroll
    for (int ct = 0; ct < 4; ++ct)
#pragma unroll
        for (int q = 0; q < 4; ++q)
            acc[ct] = __builtin_amdgcn_mfma_f32_16x16x32_bf16(a[q], wp[(ct * 4 + q) * 64],
                                                              acc[ct], 0, 0, 0);

    const int crow0 = r0 + (lane >> 4) * 4;
    const int ccol = lane & 15;
    float bv[4];
#pragma unroll
    for (int ct = 0; ct < 4; ++ct) bv[ct] = bias[ct * 16 + ccol];

#pragma unroll
    for (int j = 0; j < 4; ++j) {
        float o0 = acc[0][j] + bv[0], o1 = acc[1][j] + bv[1];
        float o2 = acc[2][j] + bv[2], o3 = acc[3][j] + bv[3];
        float m = fmaxf(fmaxf(o0, o1), fmaxf(o2, o3));
#pragma unroll
        for (int off = 1; off < 16; off <<= 1) m = fmaxf(m, __shfl_xor(m, off));
        float s = __expf(o0 - m) + __expf(o1 - m) + __expf(o2 - m) + __expf(o3 - m);
#pragma unroll
        for (int off = 1; off < 16; off <<= 1) s += __shfl_xor(s, off);
        float ml = m + __logf(s);
        int r = crow0 + j;
        if (r < N) {
            float* op = out + (size_t)r * 64 + ccol;
            op[0]  = o0 - ml;
            op[16] = o1 - ml;
            op[32] = o2 - ml;
            op[48] = o3 - ml;
        }
    }
}

extern "C" void kernel_launch(void* const* d_in, const int* in_sizes, int n_in,
                              void* d_out, int out_size, void* d_ws, size_t ws_size,
                              hipStream_t stream) {
    const float* x   = (const float*)d_in[0];
    const int*   ei  = (const int*)d_in[1];
    const float* W1  = (const float*)d_in[2];
    const float* b1  = (const float*)d_in[3];
    const float* g1  = (const float*)d_in[4];
    const float* be1 = (const float*)d_in[5];
    const float* W2  = (const float*)d_in[6];
    const float* b2  = (const float*)d_in[7];
    const float* g2  = (const float*)d_in[8];
    const float* be2 = (const float*)d_in[9];
    const float* W3  = (const float*)d_in[10];
    const float* b3  = (const float*)d_in[11];

    const int N = in_sizes[0] / 128;
    const int E = in_sizes[1] / 2;
    const int* src = ei;
    const int* dst = ei + E;

    // ---- workspace carve-up ----
    // memset region: statsPad (8192 f) + deg (N) + bhist (64) + bpos (64)
    float* statsPad = (float*)d_ws;                 // 4 x 2048 (stride-16 cols)
    float* sums1 = statsPad;
    float* sqs1  = statsPad + 2048;
    float* sums2 = statsPad + 4096;
    float* sqs2  = statsPad + 6144;
    int* deg    = (int*)(statsPad + 8192);          // N
    int* bhist  = deg + N;                          // 64
    int* bpos   = bhist + 64;                       // 64
    int* pos    = bpos + 64;                        // N
    int* rowptr = pos + N;                          // N+1
    int* bsum   = rowptr + N + 1;                   // 256
    int* perm   = bsum + 256;                       // N
    int* colidx = perm + N;                         // E
    unsigned short* hb   = (unsigned short*)(colidx + E);   // N*128 bf16 (x)
    unsigned short* rawb = hb + (size_t)N * 128;            // N*128 bf16 (gemm raw out)
    unsigned short* agb  = rawb + (size_t)N * 128;          // N*128 bf16 (agg)
    unsigned short* w1s  = agb + (size_t)N * 128;           // 16384
    unsigned short* w2s  = w1s + 16384;                     // 16384
    unsigned short* w3s  = w2s + 16384;                     // 8192

    const int nChunks = (N + 255) / 256;
    const int eBlocks = (E + 255) / 256;
    const int gemmBlocks = (N + 63) / 64;
    const int gatherBlocks = (N * 16 + 255) / 256;
    const int total4 = N * 128 / 4;
    const float invN = 1.0f / N;

    // ---- one memset: stats + deg + bhist + bpos ----
    hipMemsetAsync(statsPad, 0, 8192 * sizeof(float) + ((size_t)N + 128) * sizeof(int), stream);

    // ---- prep + CSR (+ degree-sorted perm) ----
    convert_and_prep<<<2048, 256, 0, stream>>>(x, hb, total4, W1, W2, W3, w1s, w2s, w3s);
    hist_kernel<<<eBlocks, 256, 0, stream>>>(dst, deg, E);
    scan_block<<<nChunks, 256, 0, stream>>>(deg, pos, bsum, bhist, N);
    scan_top<<<1, 256, 0, stream>>>(bsum, nChunks, bhist, bpos);
    finalize_rowptr<<<nChunks, 256, 0, stream>>>(deg, pos, bsum, rowptr, pos, bpos, perm, N, E);
    fill_kernel<<<eBlocks, 256, 0, stream>>>(src, dst, pos, colidx, E);

    // ---- layer 1 ----
    gather_agg_bf<<<gatherBlocks, 256, 0, stream>>>(hb, rowptr, colidx, perm, agb, N);
    gemm128_stats<<<gemmBlocks, 256, 0, stream>>>(agb, w1s, b1, rawb, sums1, sqs1, N);

    // ---- layer 2 (BN1+ReLU fused into gather) ----
    gather_bn_agg<<<gatherBlocks, 256, 0, stream>>>(rawb, sums1, sqs1, g1, be1, rowptr, colidx,
                                                    perm, agb, N, invN);
    gemm128_stats<<<gemmBlocks, 256, 0, stream>>>(agb, w2s, b2, rawb, sums2, sqs2, N);

    // ---- layer 3 (BN2+ReLU fused into gather; log_softmax fused into gemm) ----
    gather_bn_agg<<<gatherBlocks, 256, 0, stream>>>(rawb, sums2, sqs2, g2, be2, rowptr, colidx,
                                                    perm, agb, N, invN);
    gemm64_lsm<<<gemmBlocks, 256, 0, stream>>>(agb, w3s, b3, (float*)d_out, N);
}

// Round 6
// 291.153 us; speedup vs baseline: 1.5731x; 1.5731x over previous
//
#include <hip/hip_runtime.h>

#define BN_EPS 1e-5f

typedef __attribute__((ext_vector_type(8))) __bf16 bf16x8;
typedef __attribute__((ext_vector_type(4))) float f32x4;

__device__ __forceinline__ unsigned short f2bf(float f) {
    unsigned int u = __float_as_uint(f);
    u = (u + 0x7fffu + ((u >> 16) & 1u)) >> 16;
    return (unsigned short)u;
}
__device__ __forceinline__ float bfLo(unsigned int w) { return __uint_as_float(w << 16); }
__device__ __forceinline__ float bfHi(unsigned int w) { return __uint_as_float(w & 0xffff0000u); }

// ================= CSR construction (+ degree-bucket permutation) =================

__global__ void hist_kernel(const int* __restrict__ dst, int* __restrict__ deg, int E) {
    int e = blockIdx.x * blockDim.x + threadIdx.x;
    if (e < E) atomicAdd(&deg[dst[e]], 1);
}

// per-256-chunk inclusive scan of deg; chunk totals to bsum; ALSO 64-bucket degree histogram
__global__ void scan_block(const int* __restrict__ deg, int* __restrict__ incl,
                           int* __restrict__ bsum, int* __restrict__ bhist, int N) {
    __shared__ int s[256];
    __shared__ int bh[64];
    int i = blockIdx.x * 256 + threadIdx.x;
    int v = (i < N) ? deg[i] : 0;
    s[threadIdx.x] = v;
    if (threadIdx.x < 64) bh[threadIdx.x] = 0;
    __syncthreads();
    if (i < N) atomicAdd(&bh[v < 63 ? v : 63], 1);
#pragma unroll
    for (int off = 1; off < 256; off <<= 1) {
        int t = (threadIdx.x >= off) ? s[threadIdx.x - off] : 0;
        __syncthreads();
        s[threadIdx.x] += t;
        __syncthreads();
    }
    if (i < N) incl[i] = s[threadIdx.x];
    if (threadIdx.x == 255) bsum[blockIdx.x] = s[255];
    if (threadIdx.x < 64 && bh[threadIdx.x] > 0) atomicAdd(&bhist[threadIdx.x], bh[threadIdx.x]);
}

// single-block: exclusive scan of chunk totals (nb <= 256) AND 64-bucket exclusive scan -> bpos
__global__ void scan_top(int* __restrict__ bsum, int nb,
                         const int* __restrict__ bhist, int* __restrict__ bpos) {
    __shared__ int s[256];
    int v = (threadIdx.x < nb) ? bsum[threadIdx.x] : 0;
    s[threadIdx.x] = v;
    __syncthreads();
#pragma unroll
    for (int off = 1; off < 256; off <<= 1) {
        int t = (threadIdx.x >= off) ? s[threadIdx.x - off] : 0;
        __syncthreads();
        s[threadIdx.x] += t;
        __syncthreads();
    }
    if (threadIdx.x < nb) bsum[threadIdx.x] = s[threadIdx.x] - v;
    if (threadIdx.x < 64) {
        int bv = bhist[threadIdx.x];
        int inc = bv;
#pragma unroll
        for (int off = 1; off < 64; off <<= 1) {
            int t = __shfl_up(inc, off);
            if ((threadIdx.x & 63) >= off) inc += t;
        }
        bpos[threadIdx.x] = inc - bv;
    }
}

// rowptr/pos from scans; perm scatter via per-block LDS ranking:
// local slot from LDS atomic, block chunk from ONE global atomic per bucket per block.
__global__ void finalize_rowptr(const int* __restrict__ deg, const int* __restrict__ incl,
                                const int* __restrict__ boff, int* __restrict__ rowptr,
                                int* __restrict__ pos, int* __restrict__ bpos,
                                int* __restrict__ perm, int N, int E) {
    __shared__ int bh[64];     // block-local bucket counts
    __shared__ int bbase[64];  // block's reserved base per bucket
    int i = blockIdx.x * 256 + threadIdx.x;
    if (threadIdx.x < 64) bh[threadIdx.x] = 0;
    __syncthreads();
    int d = 0, lslot = 0, b = 0;
    if (i < N) {
        d = deg[i];
        int r = incl[i] - d + boff[i >> 8];
        rowptr[i] = r;
        pos[i] = r;
        b = d < 63 ? d : 63;
        lslot = atomicAdd(&bh[b], 1);          // LDS atomic: intra-block rank
    }
    __syncthreads();
    if (threadIdx.x < 64 && bh[threadIdx.x] > 0)
        bbase[threadIdx.x] = atomicAdd(&bpos[threadIdx.x], bh[threadIdx.x]);  // 1 global atomic/bucket/block
    __syncthreads();
    if (i < N) perm[bbase[b] + lslot] = i;
    if (i == 0) rowptr[N] = E;
}

__global__ void fill_kernel(const int* __restrict__ src, const int* __restrict__ dst,
                            int* __restrict__ pos, int* __restrict__ col, int E) {
    int e = blockIdx.x * blockDim.x + threadIdx.x;
    if (e < E) {
        int slot = atomicAdd(&pos[dst[e]], 1);
        col[slot] = src[e];
    }
}

// ============ one-time prep: x -> bf16 AND swizzle all 3 weights ============
// Wsw[((ct*4+q)*64 + l)*8 + j] = bf16( W[q*32 + (l>>4)*8 + j][ct*16 + (l&15)] )
__global__ void convert_and_prep(const float* __restrict__ x, unsigned short* __restrict__ hb,
                                 int total4,
                                 const float* __restrict__ W1, const float* __restrict__ W2,
                                 const float* __restrict__ W3,
                                 unsigned short* __restrict__ w1s, unsigned short* __restrict__ w2s,
                                 unsigned short* __restrict__ w3s) {
    int tid0 = blockIdx.x * blockDim.x + threadIdx.x;
    if (tid0 < 40960) {
        int idx = tid0;
        const float* W; unsigned short* O; int NOUT;
        if (idx < 16384)      { W = W1; O = w1s; NOUT = 128; }
        else if (idx < 32768) { W = W2; O = w2s; NOUT = 128; idx -= 16384; }
        else                  { W = W3; O = w3s; NOUT = 64;  idx -= 32768; }
        int j = idx & 7;
        int l = (idx >> 3) & 63;
        int q = (idx >> 9) & 3;
        int ct = idx >> 11;
        int k = q * 32 + ((l >> 4) & 3) * 8 + j;
        int c = ct * 16 + (l & 15);
        O[idx] = f2bf(W[(size_t)k * NOUT + c]);
    }
    int stride = gridDim.x * blockDim.x;
    for (int i = tid0; i < total4; i += stride) {
        float4 v = reinterpret_cast<const float4*>(x)[i];
        ushort4 o;
        o.x = f2bf(v.x); o.y = f2bf(v.y); o.z = f2bf(v.z); o.w = f2bf(v.w);
        reinterpret_cast<ushort4*>(hb)[i] = o;
    }
}

// ============ plain gather (layer 1): agg[i] = h[i] + sum_j h[j] ============
__global__ void gather_agg_bf(const unsigned short* __restrict__ h,
                              const int* __restrict__ rowptr, const int* __restrict__ col,
                              const int* __restrict__ perm,
                              unsigned short* __restrict__ agg, int N) {
    int t = blockIdx.x * blockDim.x + threadIdx.x;
    int ni = t >> 4;
    if (ni >= N) return;
    int node = perm[ni];
    int part = (t & 15) * 8;
    const int beg = rowptr[node], end = rowptr[node + 1];

    float acc[8];
    {
        uint4 sv = *reinterpret_cast<const uint4*>(h + (size_t)node * 128 + part);
        acc[0] = bfLo(sv.x); acc[1] = bfHi(sv.x);
        acc[2] = bfLo(sv.y); acc[3] = bfHi(sv.y);
        acc[4] = bfLo(sv.z); acc[5] = bfHi(sv.z);
        acc[6] = bfLo(sv.w); acc[7] = bfHi(sv.w);
    }
    int e = beg;
    for (; e + 1 < end; e += 2) {
        int s0 = col[e], s1 = col[e + 1];
        uint4 v0 = *reinterpret_cast<const uint4*>(h + (size_t)s0 * 128 + part);
        uint4 v1 = *reinterpret_cast<const uint4*>(h + (size_t)s1 * 128 + part);
        acc[0] += bfLo(v0.x) + bfLo(v1.x); acc[1] += bfHi(v0.x) + bfHi(v1.x);
        acc[2] += bfLo(v0.y) + bfLo(v1.y); acc[3] += bfHi(v0.y) + bfHi(v1.y);
        acc[4] += bfLo(v0.z) + bfLo(v1.z); acc[5] += bfHi(v0.z) + bfHi(v1.z);
        acc[6] += bfLo(v0.w) + bfLo(v1.w); acc[7] += bfHi(v0.w) + bfHi(v1.w);
    }
    if (e < end) {
        uint4 v0 = *reinterpret_cast<const uint4*>(h + (size_t)col[e] * 128 + part);
        acc[0] += bfLo(v0.x); acc[1] += bfHi(v0.x);
        acc[2] += bfLo(v0.y); acc[3] += bfHi(v0.y);
        acc[4] += bfLo(v0.z); acc[5] += bfHi(v0.z);
        acc[6] += bfLo(v0.w); acc[7] += bfHi(v0.w);
    }
    uint4 o;
    o.x = (unsigned int)f2bf(acc[0]) | ((unsigned int)f2bf(acc[1]) << 16);
    o.y = (unsigned int)f2bf(acc[2]) | ((unsigned int)f2bf(acc[3]) << 16);
    o.z = (unsigned int)f2bf(acc[4]) | ((unsigned int)f2bf(acc[5]) << 16);
    o.w = (unsigned int)f2bf(acc[6]) | ((unsigned int)f2bf(acc[7]) << 16);
    *reinterpret_cast<uint4*>(agg + (size_t)node * 128 + part) = o;
}

// ============ BN+ReLU-fused gather (layers 2,3), 2-edge unrolled ============
__global__ void gather_bn_agg(const unsigned short* __restrict__ raw,
                              const float* __restrict__ sumsPad, const float* __restrict__ sqsPad,
                              const float* __restrict__ g, const float* __restrict__ be,
                              const int* __restrict__ rowptr, const int* __restrict__ col,
                              const int* __restrict__ perm,
                              unsigned short* __restrict__ agg, int N, float invN) {
    int t = blockIdx.x * blockDim.x + threadIdx.x;
    int ni = t >> 4;
    if (ni >= N) return;
    int node = perm[ni];
    int part = (t & 15) * 8;
    float a8[8], c8[8];
#pragma unroll
    for (int k = 0; k < 8; ++k) {
        int c = part + k;
        float m = sumsPad[c * 16] * invN;
        float v = sqsPad[c * 16] * invN - m * m;
        float ai = g[c] * rsqrtf(v + BN_EPS);
        a8[k] = ai;
        c8[k] = be[c] - m * ai;
    }
    const int beg = rowptr[node], end = rowptr[node + 1];
    float acc[8];
    {
        uint4 sv = *reinterpret_cast<const uint4*>(raw + (size_t)node * 128 + part);
        acc[0] = fmaxf(fmaf(bfLo(sv.x), a8[0], c8[0]), 0.f);
        acc[1] = fmaxf(fmaf(bfHi(sv.x), a8[1], c8[1]), 0.f);
        acc[2] = fmaxf(fmaf(bfLo(sv.y), a8[2], c8[2]), 0.f);
        acc[3] = fmaxf(fmaf(bfHi(sv.y), a8[3], c8[3]), 0.f);
        acc[4] = fmaxf(fmaf(bfLo(sv.z), a8[4], c8[4]), 0.f);
        acc[5] = fmaxf(fmaf(bfHi(sv.z), a8[5], c8[5]), 0.f);
        acc[6] = fmaxf(fmaf(bfLo(sv.w), a8[6], c8[6]), 0.f);
        acc[7] = fmaxf(fmaf(bfHi(sv.w), a8[7], c8[7]), 0.f);
    }
    int e = beg;
    for (; e + 1 < end; e += 2) {
        int s0 = col[e], s1 = col[e + 1];
        uint4 v0 = *reinterpret_cast<const uint4*>(raw + (size_t)s0 * 128 + part);
        uint4 v1 = *reinterpret_cast<const uint4*>(raw + (size_t)s1 * 128 + part);
        acc[0] += fmaxf(fmaf(bfLo(v0.x), a8[0], c8[0]), 0.f) + fmaxf(fmaf(bfLo(v1.x), a8[0], c8[0]), 0.f);
        acc[1] += fmaxf(fmaf(bfHi(v0.x), a8[1], c8[1]), 0.f) + fmaxf(fmaf(bfHi(v1.x), a8[1], c8[1]), 0.f);
        acc[2] += fmaxf(fmaf(bfLo(v0.y), a8[2], c8[2]), 0.f) + fmaxf(fmaf(bfLo(v1.y), a8[2], c8[2]), 0.f);
        acc[3] += fmaxf(fmaf(bfHi(v0.y), a8[3], c8[3]), 0.f) + fmaxf(fmaf(bfHi(v1.y), a8[3], c8[3]), 0.f);
        acc[4] += fmaxf(fmaf(bfLo(v0.z), a8[4], c8[4]), 0.f) + fmaxf(fmaf(bfLo(v1.z), a8[4], c8[4]), 0.f);
        acc[5] += fmaxf(fmaf(bfHi(v0.z), a8[5], c8[5]), 0.f) + fmaxf(fmaf(bfHi(v1.z), a8[5], c8[5]), 0.f);
        acc[6] += fmaxf(fmaf(bfLo(v0.w), a8[6], c8[6]), 0.f) + fmaxf(fmaf(bfLo(v1.w), a8[6], c8[6]), 0.f);
        acc[7] += fmaxf(fmaf(bfHi(v0.w), a8[7], c8[7]), 0.f) + fmaxf(fmaf(bfHi(v1.w), a8[7], c8[7]), 0.f);
    }
    if (e < end) {
        uint4 v0 = *reinterpret_cast<const uint4*>(raw + (size_t)col[e] * 128 + part);
        acc[0] += fmaxf(fmaf(bfLo(v0.x), a8[0], c8[0]), 0.f);
        acc[1] += fmaxf(fmaf(bfHi(v0.x), a8[1], c8[1]), 0.f);
        acc[2] += fmaxf(fmaf(bfLo(v0.y), a8[2], c8[2]), 0.f);
        acc[3] += fmaxf(fmaf(bfHi(v0.y), a8[3], c8[3]), 0.f);
        acc[4] += fmaxf(fmaf(bfLo(v0.z), a8[4], c8[4]), 0.f);
        acc[5] += fmaxf(fmaf(bfHi(v0.z), a8[5], c8[5]), 0.f);
        acc[6] += fmaxf(fmaf(bfLo(v0.w), a8[6], c8[6]), 0.f);
        acc[7] += fmaxf(fmaf(bfHi(v0.w), a8[7], c8[7]), 0.f);
    }
    uint4 o;
    o.x = (unsigned int)f2bf(acc[0]) | ((unsigned int)f2bf(acc[1]) << 16);
    o.y = (unsigned int)f2bf(acc[2]) | ((unsigned int)f2bf(acc[3]) << 16);
    o.z = (unsigned int)f2bf(acc[4]) | ((unsigned int)f2bf(acc[5]) << 16);
    o.w = (unsigned int)f2bf(acc[6]) | ((unsigned int)f2bf(acc[7]) << 16);
    *reinterpret_cast<uint4*>(agg + (size_t)node * 128 + part) = o;
}

// ========== MFMA GEMM (NOUT=128) + bias + fused column stats; bf16 raw out ==========
__global__ __launch_bounds__(256) void gemm128_stats(const unsigned short* __restrict__ A,
                                                     const unsigned short* __restrict__ Wsw,
                                                     const float* __restrict__ bias,
                                                     unsigned short* __restrict__ outb,
                                                     float* __restrict__ sumsPad,
                                                     float* __restrict__ sqsPad, int N) {
    __shared__ float red[2][4][128];
    const int lane = threadIdx.x & 63;
    const int w = threadIdx.x >> 6;
    const int r0 = blockIdx.x * 64 + w * 16;
    int arow = r0 + (lane & 15);
    if (arow >= N) arow = N - 1;
    const int kb = lane >> 4;
    const unsigned short* ap = A + (size_t)arow * 128 + kb * 8;

    bf16x8 a[4];
#pragma unroll
    for (int q = 0; q < 4; ++q) a[q] = *reinterpret_cast<const bf16x8*>(ap + q * 32);

    f32x4 acc[8];
#pragma unroll
    for (int ct = 0; ct < 8; ++ct) acc[ct] = (f32x4){0.f, 0.f, 0.f, 0.f};

    const bf16x8* wp = reinterpret_cast<const bf16x8*>(Wsw) + lane;
#pragma unroll
    for (int ct = 0; ct < 8; ++ct)
#pragma unroll
        for (int q = 0; q < 4; ++q)
            acc[ct] = __builtin_amdgcn_mfma_f32_16x16x32_bf16(a[q], wp[(ct * 4 + q) * 64],
                                                              acc[ct], 0, 0, 0);

    const int crow0 = r0 + (lane >> 4) * 4;
    const int ccol = lane & 15;
#pragma unroll
    for (int ct = 0; ct < 8; ++ct) {
        int c = ct * 16 + ccol;
        float bv = bias[c];
        float s = 0.f, qq = 0.f;
#pragma unroll
        for (int j = 0; j < 4; ++j) {
            int r = crow0 + j;
            if (r < N) {
                float o = acc[ct][j] + bv;
                outb[(size_t)r * 128 + c] = f2bf(o);
                s += o; qq += o * o;
            }
        }
        s += __shfl_xor(s, 16); s += __shfl_xor(s, 32);
        qq += __shfl_xor(qq, 16); qq += __shfl_xor(qq, 32);
        if (lane < 16) { red[0][w][c] = s; red[1][w][c] = qq; }
    }
    __syncthreads();
    int tid = threadIdx.x;
    if (tid < 128) {
        float S = red[0][0][tid] + red[0][1][tid] + red[0][2][tid] + red[0][3][tid];
        atomicAdd(&sumsPad[tid * 16], S);
    } else {
        int c = tid - 128;
        float Q = red[1][0][c] + red[1][1][c] + red[1][2][c] + red[1][3][c];
        atomicAdd(&sqsPad[c * 16], Q);
    }
}

// ========== MFMA GEMM (NOUT=64) + bias + fused log_softmax ==========
__global__ __launch_bounds__(256) void gemm64_lsm(const unsigned short* __restrict__ A,
                                                  const unsigned short* __restrict__ Wsw,
                                                  const float* __restrict__ bias,
                                                  float* __restrict__ out, int N) {
    const int lane = threadIdx.x & 63;
    const int w = threadIdx.x >> 6;
    const int r0 = blockIdx.x * 64 + w * 16;
    int arow = r0 + (lane & 15);
    if (arow >= N) arow = N - 1;
    const int kb = lane >> 4;
    const unsigned short* ap = A + (size_t)arow * 128 + kb * 8;

    bf16x8 a[4];
#pragma unroll
    for (int q = 0; q < 4; ++q) a[q] = *reinterpret_cast<const bf16x8*>(ap + q * 32);

    f32x4 acc[4];
#pragma unroll
    for (int ct = 0; ct < 4; ++ct) acc[ct] = (f32x4){0.f, 0.f, 0.f, 0.f};

    const bf16x8* wp = reinterpret_cast<const bf16x8*>(Wsw) + lane;
#pragma unroll
    for (int ct = 0; ct < 4; ++ct)
#pragma unroll
        for (int q = 0; q < 4; ++q)
            acc[ct] = __builtin_amdgcn_mfma_f32_16x16x32_bf16(a[q], wp[(ct * 4 + q) * 64],
                                                              acc[ct], 0, 0, 0);

    const int crow0 = r0 + (lane >> 4) * 4;
    const int ccol = lane & 15;
    float bv[4];
#pragma unroll
    for (int ct = 0; ct < 4; ++ct) bv[ct] = bias[ct * 16 + ccol];

#pragma unroll
    for (int j = 0; j < 4; ++j) {
        float o0 = acc[0][j] + bv[0], o1 = acc[1][j] + bv[1];
        float o2 = acc[2][j] + bv[2], o3 = acc[3][j] + bv[3];
        float m = fmaxf(fmaxf(o0, o1), fmaxf(o2, o3));
#pragma unroll
        for (int off = 1; off < 16; off <<= 1) m = fmaxf(m, __shfl_xor(m, off));
        float s = __expf(o0 - m) + __expf(o1 - m) + __expf(o2 - m) + __expf(o3 - m);
#pragma unroll
        for (int off = 1; off < 16; off <<= 1) s += __shfl_xor(s, off);
        float ml = m + __logf(s);
        int r = crow0 + j;
        if (r < N) {
            float* op = out + (size_t)r * 64 + ccol;
            op[0]  = o0 - ml;
            op[16] = o1 - ml;
            op[32] = o2 - ml;
            op[48] = o3 - ml;
        }
    }
}

extern "C" void kernel_launch(void* const* d_in, const int* in_sizes, int n_in,
                              void* d_out, int out_size, void* d_ws, size_t ws_size,
                              hipStream_t stream) {
    const float* x   = (const float*)d_in[0];
    const int*   ei  = (const int*)d_in[1];
    const float* W1  = (const float*)d_in[2];
    const float* b1  = (const float*)d_in[3];
    const float* g1  = (const float*)d_in[4];
    const float* be1 = (const float*)d_in[5];
    const float* W2  = (const float*)d_in[6];
    const float* b2  = (const float*)d_in[7];
    const float* g2  = (const float*)d_in[8];
    const float* be2 = (const float*)d_in[9];
    const float* W3  = (const float*)d_in[10];
    const float* b3  = (const float*)d_in[11];

    const int N = in_sizes[0] / 128;
    const int E = in_sizes[1] / 2;
    const int* src = ei;
    const int* dst = ei + E;

    // ---- workspace carve-up ----
    // memset region: statsPad (8192 f) + deg (N) + bhist (64) + bpos (64)
    float* statsPad = (float*)d_ws;                 // 4 x 2048 (stride-16 cols)
    float* sums1 = statsPad;
    float* sqs1  = statsPad + 2048;
    float* sums2 = statsPad + 4096;
    float* sqs2  = statsPad + 6144;
    int* deg    = (int*)(statsPad + 8192);          // N
    int* bhist  = deg + N;                          // 64
    int* bpos   = bhist + 64;                       // 64
    int* pos    = bpos + 64;                        // N
    int* rowptr = pos + N;                          // N+1
    int* bsum   = rowptr + N + 1;                   // 256
    int* perm   = bsum + 256;                       // N
    int* colidx = perm + N;                         // E
    unsigned short* hb   = (unsigned short*)(colidx + E);   // N*128 bf16 (x)
    unsigned short* rawb = hb + (size_t)N * 128;            // N*128 bf16 (gemm raw out)
    unsigned short* agb  = rawb + (size_t)N * 128;          // N*128 bf16 (agg)
    unsigned short* w1s  = agb + (size_t)N * 128;           // 16384
    unsigned short* w2s  = w1s + 16384;                     // 16384
    unsigned short* w3s  = w2s + 16384;                     // 8192

    const int nChunks = (N + 255) / 256;
    const int eBlocks = (E + 255) / 256;
    const int gemmBlocks = (N + 63) / 64;
    const int gatherBlocks = (N * 16 + 255) / 256;
    const int total4 = N * 128 / 4;
    const float invN = 1.0f / N;

    // ---- one memset: stats + deg + bhist + bpos ----
    hipMemsetAsync(statsPad, 0, 8192 * sizeof(float) + ((size_t)N + 128) * sizeof(int), stream);

    // ---- prep + CSR (+ degree-sorted perm) ----
    convert_and_prep<<<2048, 256, 0, stream>>>(x, hb, total4, W1, W2, W3, w1s, w2s, w3s);
    hist_kernel<<<eBlocks, 256, 0, stream>>>(dst, deg, E);
    scan_block<<<nChunks, 256, 0, stream>>>(deg, pos, bsum, bhist, N);
    scan_top<<<1, 256, 0, stream>>>(bsum, nChunks, bhist, bpos);
    finalize_rowptr<<<nChunks, 256, 0, stream>>>(deg, pos, bsum, rowptr, pos, bpos, perm, N, E);
    fill_kernel<<<eBlocks, 256, 0, stream>>>(src, dst, pos, colidx, E);

    // ---- layer 1 ----
    gather_agg_bf<<<gatherBlocks, 256, 0, stream>>>(hb, rowptr, colidx, perm, agb, N);
    gemm128_stats<<<gemmBlocks, 256, 0, stream>>>(agb, w1s, b1, rawb, sums1, sqs1, N);

    // ---- layer 2 (BN1+ReLU fused into gather) ----
    gather_bn_agg<<<gatherBlocks, 256, 0, stream>>>(rawb, sums1, sqs1, g1, be1, rowptr, colidx,
                                                    perm, agb, N, invN);
    gemm128_stats<<<gemmBlocks, 256, 0, stream>>>(agb, w2s, b2, rawb, sums2, sqs2, N);

    // ---- layer 3 (BN2+ReLU fused into gather; log_softmax fused into gemm) ----
    gather_bn_agg<<<gatherBlocks, 256, 0, stream>>>(rawb, sums2, sqs2, g2, be2, rowptr, colidx,
                                                    perm, agb, N, invN);
    gemm64_lsm<<<gemmBlocks, 256, 0, stream>>>(agb, w3s, b3, (float*)d_out, N);
}

// Round 7
// 252.474 us; speedup vs baseline: 1.8141x; 1.1532x over previous
//
#include <hip/hip_runtime.h>

#define BN_EPS 1e-5f

typedef __attribute__((ext_vector_type(8))) __bf16 bf16x8;
typedef __attribute__((ext_vector_type(4))) float f32x4;

__device__ __forceinline__ unsigned short f2bf(float f) {
    unsigned int u = __float_as_uint(f);
    u = (u + 0x7fffu + ((u >> 16) & 1u)) >> 16;
    return (unsigned short)u;
}
__device__ __forceinline__ float bfLo(unsigned int w) { return __uint_as_float(w << 16); }
__device__ __forceinline__ float bfHi(unsigned int w) { return __uint_as_float(w & 0xffff0000u); }

__device__ __forceinline__ void accRow(float* acc, uint4 v) {
    acc[0] += bfLo(v.x); acc[1] += bfHi(v.x);
    acc[2] += bfLo(v.y); acc[3] += bfHi(v.y);
    acc[4] += bfLo(v.z); acc[5] += bfHi(v.z);
    acc[6] += bfLo(v.w); acc[7] += bfHi(v.w);
}
__device__ __forceinline__ void accRowBN(float* acc, uint4 v, const float* a8, const float* c8) {
    acc[0] += fmaxf(fmaf(bfLo(v.x), a8[0], c8[0]), 0.f);
    acc[1] += fmaxf(fmaf(bfHi(v.x), a8[1], c8[1]), 0.f);
    acc[2] += fmaxf(fmaf(bfLo(v.y), a8[2], c8[2]), 0.f);
    acc[3] += fmaxf(fmaf(bfHi(v.y), a8[3], c8[3]), 0.f);
    acc[4] += fmaxf(fmaf(bfLo(v.z), a8[4], c8[4]), 0.f);
    acc[5] += fmaxf(fmaf(bfHi(v.z), a8[5], c8[5]), 0.f);
    acc[6] += fmaxf(fmaf(bfLo(v.w), a8[6], c8[6]), 0.f);
    acc[7] += fmaxf(fmaf(bfHi(v.w), a8[7], c8[7]), 0.f);
}

// ================= CSR construction =================

__global__ void hist_kernel(const int* __restrict__ dst, int* __restrict__ deg, int E) {
    int e = blockIdx.x * blockDim.x + threadIdx.x;
    if (e < E) atomicAdd(&deg[dst[e]], 1);
}

__global__ void scan_block(const int* __restrict__ deg, int* __restrict__ incl,
                           int* __restrict__ bsum, int N) {
    __shared__ int s[256];
    int i = blockIdx.x * 256 + threadIdx.x;
    int v = (i < N) ? deg[i] : 0;
    s[threadIdx.x] = v;
    __syncthreads();
#pragma unroll
    for (int off = 1; off < 256; off <<= 1) {
        int t = (threadIdx.x >= off) ? s[threadIdx.x - off] : 0;
        __syncthreads();
        s[threadIdx.x] += t;
        __syncthreads();
    }
    if (i < N) incl[i] = s[threadIdx.x];
    if (threadIdx.x == 255) bsum[blockIdx.x] = s[255];
}

__global__ void scan_top(int* __restrict__ bsum, int nb) {
    __shared__ int s[256];
    int v = (threadIdx.x < nb) ? bsum[threadIdx.x] : 0;
    s[threadIdx.x] = v;
    __syncthreads();
#pragma unroll
    for (int off = 1; off < 256; off <<= 1) {
        int t = (threadIdx.x >= off) ? s[threadIdx.x - off] : 0;
        __syncthreads();
        s[threadIdx.x] += t;
        __syncthreads();
    }
    if (threadIdx.x < nb) bsum[threadIdx.x] = s[threadIdx.x] - v;
}

__global__ void finalize_rowptr(const int* __restrict__ deg, const int* __restrict__ incl,
                                const int* __restrict__ boff, int* __restrict__ rowptr,
                                int* __restrict__ pos, int N, int E) {
    int i = blockIdx.x * 256 + threadIdx.x;
    if (i < N) {
        int r = incl[i] - deg[i] + boff[i >> 8];
        rowptr[i] = r;
        pos[i] = r;
    }
    if (i == 0) rowptr[N] = E;
}

__global__ void fill_kernel(const int* __restrict__ src, const int* __restrict__ dst,
                            int* __restrict__ pos, int* __restrict__ col, int E) {
    int e = blockIdx.x * blockDim.x + threadIdx.x;
    if (e < E) {
        int slot = atomicAdd(&pos[dst[e]], 1);
        col[slot] = src[e];
    }
}

// ============ one-time prep: x -> bf16 AND swizzle all 3 weights ============
// Wsw[((ct*4+q)*64 + l)*8 + j] = bf16( W[q*32 + (l>>4)*8 + j][ct*16 + (l&15)] )
__global__ void convert_and_prep(const float* __restrict__ x, unsigned short* __restrict__ hb,
                                 int total4,
                                 const float* __restrict__ W1, const float* __restrict__ W2,
                                 const float* __restrict__ W3,
                                 unsigned short* __restrict__ w1s, unsigned short* __restrict__ w2s,
                                 unsigned short* __restrict__ w3s) {
    int tid0 = blockIdx.x * blockDim.x + threadIdx.x;
    if (tid0 < 40960) {
        int idx = tid0;
        const float* W; unsigned short* O; int NOUT;
        if (idx < 16384)      { W = W1; O = w1s; NOUT = 128; }
        else if (idx < 32768) { W = W2; O = w2s; NOUT = 128; idx -= 16384; }
        else                  { W = W3; O = w3s; NOUT = 64;  idx -= 32768; }
        int j = idx & 7;
        int l = (idx >> 3) & 63;
        int q = (idx >> 9) & 3;
        int ct = idx >> 11;
        int k = q * 32 + ((l >> 4) & 3) * 8 + j;
        int c = ct * 16 + (l & 15);
        O[idx] = f2bf(W[(size_t)k * NOUT + c]);
    }
    int stride = gridDim.x * blockDim.x;
    for (int i = tid0; i < total4; i += stride) {
        float4 v = reinterpret_cast<const float4*>(x)[i];
        ushort4 o;
        o.x = f2bf(v.x); o.y = f2bf(v.y); o.z = f2bf(v.z); o.w = f2bf(v.w);
        reinterpret_cast<ushort4*>(hb)[i] = o;
    }
}

// ============ plain gather (layer 1): agg[i] = h[i] + sum_j h[j], 4-edge unroll ============
__global__ void gather_agg_bf(const unsigned short* __restrict__ h,
                              const int* __restrict__ rowptr, const int* __restrict__ col,
                              unsigned short* __restrict__ agg, int N) {
    int t = blockIdx.x * blockDim.x + threadIdx.x;
    int node = t >> 4;
    if (node >= N) return;
    int part = (t & 15) * 8;
    const unsigned short* hp = h + part;
    const int beg = rowptr[node], end = rowptr[node + 1];

    float acc[8];
    {
        uint4 sv = *reinterpret_cast<const uint4*>(hp + (size_t)node * 128);
        acc[0] = bfLo(sv.x); acc[1] = bfHi(sv.x);
        acc[2] = bfLo(sv.y); acc[3] = bfHi(sv.y);
        acc[4] = bfLo(sv.z); acc[5] = bfHi(sv.z);
        acc[6] = bfLo(sv.w); acc[7] = bfHi(sv.w);
    }
    int e = beg;
    for (; e + 3 < end; e += 4) {
        int s0 = col[e], s1 = col[e + 1], s2 = col[e + 2], s3 = col[e + 3];
        uint4 v0 = *reinterpret_cast<const uint4*>(hp + (size_t)s0 * 128);
        uint4 v1 = *reinterpret_cast<const uint4*>(hp + (size_t)s1 * 128);
        uint4 v2 = *reinterpret_cast<const uint4*>(hp + (size_t)s2 * 128);
        uint4 v3 = *reinterpret_cast<const uint4*>(hp + (size_t)s3 * 128);
        accRow(acc, v0); accRow(acc, v1); accRow(acc, v2); accRow(acc, v3);
    }
    for (; e < end; ++e)
        accRow(acc, *reinterpret_cast<const uint4*>(hp + (size_t)col[e] * 128));

    uint4 o;
    o.x = (unsigned int)f2bf(acc[0]) | ((unsigned int)f2bf(acc[1]) << 16);
    o.y = (unsigned int)f2bf(acc[2]) | ((unsigned int)f2bf(acc[3]) << 16);
    o.z = (unsigned int)f2bf(acc[4]) | ((unsigned int)f2bf(acc[5]) << 16);
    o.w = (unsigned int)f2bf(acc[6]) | ((unsigned int)f2bf(acc[7]) << 16);
    *reinterpret_cast<uint4*>(agg + (size_t)node * 128 + part) = o;
}

// ============ BN+ReLU-fused gather (layer 2), 4-edge unroll ============
__global__ void gather_bn_agg(const unsigned short* __restrict__ raw,
                              const float* __restrict__ sumsPad, const float* __restrict__ sqsPad,
                              const float* __restrict__ g, const float* __restrict__ be,
                              const int* __restrict__ rowptr, const int* __restrict__ col,
                              unsigned short* __restrict__ agg, int N, float invN) {
    int t = blockIdx.x * blockDim.x + threadIdx.x;
    int node = t >> 4;
    if (node >= N) return;
    int part = (t & 15) * 8;
    const unsigned short* rp = raw + part;
    float a8[8], c8[8];
#pragma unroll
    for (int k = 0; k < 8; ++k) {
        int c = part + k;
        float m = sumsPad[c * 16] * invN;
        float v = sqsPad[c * 16] * invN - m * m;
        float ai = g[c] * rsqrtf(v + BN_EPS);
        a8[k] = ai;
        c8[k] = be[c] - m * ai;
    }
    const int beg = rowptr[node], end = rowptr[node + 1];
    float acc[8] = {0.f, 0.f, 0.f, 0.f, 0.f, 0.f, 0.f, 0.f};
    accRowBN(acc, *reinterpret_cast<const uint4*>(rp + (size_t)node * 128), a8, c8);  // self
    int e = beg;
    for (; e + 3 < end; e += 4) {
        int s0 = col[e], s1 = col[e + 1], s2 = col[e + 2], s3 = col[e + 3];
        uint4 v0 = *reinterpret_cast<const uint4*>(rp + (size_t)s0 * 128);
        uint4 v1 = *reinterpret_cast<const uint4*>(rp + (size_t)s1 * 128);
        uint4 v2 = *reinterpret_cast<const uint4*>(rp + (size_t)s2 * 128);
        uint4 v3 = *reinterpret_cast<const uint4*>(rp + (size_t)s3 * 128);
        accRowBN(acc, v0, a8, c8); accRowBN(acc, v1, a8, c8);
        accRowBN(acc, v2, a8, c8); accRowBN(acc, v3, a8, c8);
    }
    for (; e < end; ++e)
        accRowBN(acc, *reinterpret_cast<const uint4*>(rp + (size_t)col[e] * 128), a8, c8);

    uint4 o;
    o.x = (unsigned int)f2bf(acc[0]) | ((unsigned int)f2bf(acc[1]) << 16);
    o.y = (unsigned int)f2bf(acc[2]) | ((unsigned int)f2bf(acc[3]) << 16);
    o.z = (unsigned int)f2bf(acc[4]) | ((unsigned int)f2bf(acc[5]) << 16);
    o.w = (unsigned int)f2bf(acc[6]) | ((unsigned int)f2bf(acc[7]) << 16);
    *reinterpret_cast<uint4*>(agg + (size_t)node * 128 + part) = o;
}

// ========== MFMA GEMM (NOUT=128) + bias + fused column stats; bf16 raw out ==========
__global__ __launch_bounds__(256) void gemm128_stats(const unsigned short* __restrict__ A,
                                                     const unsigned short* __restrict__ Wsw,
                                                     const float* __restrict__ bias,
                                                     unsigned short* __restrict__ outb,
                                                     float* __restrict__ sumsPad,
                                                     float* __restrict__ sqsPad, int N) {
    __shared__ float red[2][4][128];
    const int lane = threadIdx.x & 63;
    const int w = threadIdx.x >> 6;
    const int r0 = blockIdx.x * 64 + w * 16;
    int arow = r0 + (lane & 15);
    if (arow >= N) arow = N - 1;
    const int kb = lane >> 4;
    const unsigned short* ap = A + (size_t)arow * 128 + kb * 8;

    bf16x8 a[4];
#pragma unroll
    for (int q = 0; q < 4; ++q) a[q] = *reinterpret_cast<const bf16x8*>(ap + q * 32);

    f32x4 acc[8];
#pragma unroll
    for (int ct = 0; ct < 8; ++ct) acc[ct] = (f32x4){0.f, 0.f, 0.f, 0.f};

    const bf16x8* wp = reinterpret_cast<const bf16x8*>(Wsw) + lane;
#pragma unroll
    for (int ct = 0; ct < 8; ++ct)
#pragma unroll
        for (int q = 0; q < 4; ++q)
            acc[ct] = __builtin_amdgcn_mfma_f32_16x16x32_bf16(a[q], wp[(ct * 4 + q) * 64],
                                                              acc[ct], 0, 0, 0);

    const int crow0 = r0 + (lane >> 4) * 4;
    const int ccol = lane & 15;
#pragma unroll
    for (int ct = 0; ct < 8; ++ct) {
        int c = ct * 16 + ccol;
        float bv = bias[c];
        float s = 0.f, qq = 0.f;
#pragma unroll
        for (int j = 0; j < 4; ++j) {
            int r = crow0 + j;
            if (r < N) {
                float o = acc[ct][j] + bv;
                outb[(size_t)r * 128 + c] = f2bf(o);
                s += o; qq += o * o;
            }
        }
        s += __shfl_xor(s, 16); s += __shfl_xor(s, 32);
        qq += __shfl_xor(qq, 16); qq += __shfl_xor(qq, 32);
        if (lane < 16) { red[0][w][c] = s; red[1][w][c] = qq; }
    }
    __syncthreads();
    int tid = threadIdx.x;
    if (tid < 128) {
        float S = red[0][0][tid] + red[0][1][tid] + red[0][2][tid] + red[0][3][tid];
        atomicAdd(&sumsPad[tid * 16], S);
    } else {
        int c = tid - 128;
        float Q = red[1][0][c] + red[1][1][c] + red[1][2][c] + red[1][3][c];
        atomicAdd(&sqsPad[c * 16], Q);
    }
}

// ========== MFMA GEMM (NOUT=64) with inline BN2+ReLU on A; M = relu(bn(raw)) @ W3 (NO bias) ==========
__global__ __launch_bounds__(256) void gemm64_bn(const unsigned short* __restrict__ raw,
                                                 const float* __restrict__ sumsPad,
                                                 const float* __restrict__ sqsPad,
                                                 const float* __restrict__ g,
                                                 const float* __restrict__ be,
                                                 const unsigned short* __restrict__ Wsw,
                                                 unsigned short* __restrict__ M, int N,
                                                 float invN) {
    const int lane = threadIdx.x & 63;
    const int w = threadIdx.x >> 6;
    const int r0 = blockIdx.x * 64 + w * 16;
    int arow = r0 + (lane & 15);
    if (arow >= N) arow = N - 1;
    const int kb = lane >> 4;
    const unsigned short* ap = raw + (size_t)arow * 128 + kb * 8;

    bf16x8 a[4];
#pragma unroll
    for (int q = 0; q < 4; ++q) {
        uint4 rv = *reinterpret_cast<const uint4*>(ap + q * 32);
        float e0 = bfLo(rv.x), e1 = bfHi(rv.x), e2 = bfLo(rv.y), e3 = bfHi(rv.y);
        float e4 = bfLo(rv.z), e5 = bfHi(rv.z), e6 = bfLo(rv.w), e7 = bfHi(rv.w);
        float hh[8] = {e0, e1, e2, e3, e4, e5, e6, e7};
        uint4 hp;
        unsigned int pk[4];
#pragma unroll
        for (int p = 0; p < 4; ++p) {
            unsigned int lohi[2];
#pragma unroll
            for (int hl = 0; hl < 2; ++hl) {
                int j = p * 2 + hl;
                int c = q * 32 + kb * 8 + j;
                float mcol = sumsPad[c * 16] * invN;
                float var = sqsPad[c * 16] * invN - mcol * mcol;
                float ai = g[c] * rsqrtf(var + BN_EPS);
                float ci = be[c] - mcol * ai;
                lohi[hl] = f2bf(fmaxf(fmaf(hh[j], ai, ci), 0.f));
            }
            pk[p] = lohi[0] | (lohi[1] << 16);
        }
        hp.x = pk[0]; hp.y = pk[1]; hp.z = pk[2]; hp.w = pk[3];
        a[q] = *reinterpret_cast<bf16x8*>(&hp);
    }

    f32x4 acc[4];
#pragma unroll
    for (int ct = 0; ct < 4; ++ct) acc[ct] = (f32x4){0.f, 0.f, 0.f, 0.f};

    const bf16x8* wp = reinterpret_cast<const bf16x8*>(Wsw) + lane;
#pragma unroll
    for (int ct = 0; ct < 4; ++ct)
#pragma unroll
        for (int q = 0; q < 4; ++q)
            acc[ct] = __builtin_amdgcn_mfma_f32_16x16x32_bf16(a[q], wp[(ct * 4 + q) * 64],
                                                              acc[ct], 0, 0, 0);

    const int crow0 = r0 + (lane >> 4) * 4;
    const int ccol = lane & 15;
#pragma unroll
    for (int ct = 0; ct < 4; ++ct) {
        int c = ct * 16 + ccol;
#pragma unroll
        for (int j = 0; j < 4; ++j) {
            int r = crow0 + j;
            if (r < N) M[(size_t)r * 64 + c] = f2bf(acc[ct][j]);
        }
    }
}

// ========== layer-3 gather on M (64-wide) + bias + log_softmax; 8 lanes/node ==========
__global__ void gather64_lsm(const unsigned short* __restrict__ M,
                             const int* __restrict__ rowptr, const int* __restrict__ col,
                             const float* __restrict__ bias, float* __restrict__ out, int N) {
    int t = blockIdx.x * blockDim.x + threadIdx.x;
    int node = t >> 3;
    if (node >= N) return;
    int part = (t & 7) * 8;
    const unsigned short* mp = M + part;
    const int beg = rowptr[node], end = rowptr[node + 1];

    float acc[8];
    {
        uint4 sv = *reinterpret_cast<const uint4*>(mp + (size_t)node * 64);
        acc[0] = bfLo(sv.x); acc[1] = bfHi(sv.x);
        acc[2] = bfLo(sv.y); acc[3] = bfHi(sv.y);
        acc[4] = bfLo(sv.z); acc[5] = bfHi(sv.z);
        acc[6] = bfLo(sv.w); acc[7] = bfHi(sv.w);
    }
    int e = beg;
    for (; e + 3 < end; e += 4) {
        int s0 = col[e], s1 = col[e + 1], s2 = col[e + 2], s3 = col[e + 3];
        uint4 v0 = *reinterpret_cast<const uint4*>(mp + (size_t)s0 * 64);
        uint4 v1 = *reinterpret_cast<const uint4*>(mp + (size_t)s1 * 64);
        uint4 v2 = *reinterpret_cast<const uint4*>(mp + (size_t)s2 * 64);
        uint4 v3 = *reinterpret_cast<const uint4*>(mp + (size_t)s3 * 64);
        accRow(acc, v0); accRow(acc, v1); accRow(acc, v2); accRow(acc, v3);
    }
    for (; e < end; ++e)
        accRow(acc, *reinterpret_cast<const uint4*>(mp + (size_t)col[e] * 64));

#pragma unroll
    for (int k = 0; k < 8; ++k) acc[k] += bias[part + k];

    // log_softmax over 64 values spread across 8 lanes (octet) x 8 regs
    float m = acc[0];
#pragma unroll
    for (int k = 1; k < 8; ++k) m = fmaxf(m, acc[k]);
#pragma unroll
    for (int off = 1; off < 8; off <<= 1) m = fmaxf(m, __shfl_xor(m, off));
    float s = 0.f;
#pragma unroll
    for (int k = 0; k < 8; ++k) s += __expf(acc[k] - m);
#pragma unroll
    for (int off = 1; off < 8; off <<= 1) s += __shfl_xor(s, off);
    float ml = m + __logf(s);

    float4 o0, o1;
    o0.x = acc[0] - ml; o0.y = acc[1] - ml; o0.z = acc[2] - ml; o0.w = acc[3] - ml;
    o1.x = acc[4] - ml; o1.y = acc[5] - ml; o1.z = acc[6] - ml; o1.w = acc[7] - ml;
    float* op = out + (size_t)node * 64 + part;
    *reinterpret_cast<float4*>(op) = o0;
    *reinterpret_cast<float4*>(op + 4) = o1;
}

extern "C" void kernel_launch(void* const* d_in, const int* in_sizes, int n_in,
                              void* d_out, int out_size, void* d_ws, size_t ws_size,
                              hipStream_t stream) {
    const float* x   = (const float*)d_in[0];
    const int*   ei  = (const int*)d_in[1];
    const float* W1  = (const float*)d_in[2];
    const float* b1  = (const float*)d_in[3];
    const float* g1  = (const float*)d_in[4];
    const float* be1 = (const float*)d_in[5];
    const float* W2  = (const float*)d_in[6];
    const float* b2  = (const float*)d_in[7];
    const float* g2  = (const float*)d_in[8];
    const float* be2 = (const float*)d_in[9];
    const float* W3  = (const float*)d_in[10];
    const float* b3  = (const float*)d_in[11];

    const int N = in_sizes[0] / 128;
    const int E = in_sizes[1] / 2;
    const int* src = ei;
    const int* dst = ei + E;

    // ---- workspace carve-up ----
    float* statsPad = (float*)d_ws;                 // 4 x 2048 (stride-16 cols)
    float* sums1 = statsPad;
    float* sqs1  = statsPad + 2048;
    float* sums2 = statsPad + 4096;
    float* sqs2  = statsPad + 6144;
    int* deg    = (int*)(statsPad + 8192);          // N   (memset with stats)
    int* pos    = deg + N;                          // N
    int* rowptr = pos + N;                          // N+1
    int* bsum   = rowptr + N + 1;                   // 256
    int* colidx = bsum + 256;                       // E
    unsigned short* hb   = (unsigned short*)(colidx + E);   // N*128 bf16 (x)
    unsigned short* rawb = hb + (size_t)N * 128;            // N*128 bf16 (gemm raw out)
    unsigned short* agb  = rawb + (size_t)N * 128;          // N*128 bf16 (agg)
    unsigned short* m3   = agb + (size_t)N * 128;           // N*64 bf16 (layer3 pre-agg)
    unsigned short* w1s  = m3 + (size_t)N * 64;             // 16384
    unsigned short* w2s  = w1s + 16384;                     // 16384
    unsigned short* w3s  = w2s + 16384;                     // 8192

    const int nChunks = (N + 255) / 256;
    const int eBlocks = (E + 255) / 256;
    const int gemmBlocks = (N + 63) / 64;
    const int gatherBlocks = (N * 16 + 255) / 256;
    const int gather64Blocks = (N * 8 + 255) / 256;
    const int total4 = N * 128 / 4;
    const float invN = 1.0f / N;

    // ---- one memset: stats + deg ----
    hipMemsetAsync(statsPad, 0, 8192 * sizeof(float) + (size_t)N * sizeof(int), stream);

    // ---- prep + CSR ----
    convert_and_prep<<<2048, 256, 0, stream>>>(x, hb, total4, W1, W2, W3, w1s, w2s, w3s);
    hist_kernel<<<eBlocks, 256, 0, stream>>>(dst, deg, E);
    scan_block<<<nChunks, 256, 0, stream>>>(deg, pos, bsum, N);
    scan_top<<<1, 256, 0, stream>>>(bsum, nChunks);
    finalize_rowptr<<<nChunks, 256, 0, stream>>>(deg, pos, bsum, rowptr, pos, N, E);
    fill_kernel<<<eBlocks, 256, 0, stream>>>(src, dst, pos, colidx, E);

    // ---- layer 1 ----
    gather_agg_bf<<<gatherBlocks, 256, 0, stream>>>(hb, rowptr, colidx, agb, N);
    gemm128_stats<<<gemmBlocks, 256, 0, stream>>>(agb, w1s, b1, rawb, sums1, sqs1, N);

    // ---- layer 2 (BN1+ReLU fused into gather) ----
    gather_bn_agg<<<gatherBlocks, 256, 0, stream>>>(rawb, sums1, sqs1, g1, be1, rowptr, colidx,
                                                    agb, N, invN);
    gemm128_stats<<<gemmBlocks, 256, 0, stream>>>(agb, w2s, b2, rawb, sums2, sqs2, N);

    // ---- layer 3: GEMM first (BN2+ReLU inline), then 64-wide gather + bias + lsm ----
    gemm64_bn<<<gemmBlocks, 256, 0, stream>>>(rawb, sums2, sqs2, g2, be2, w3s, m3, N, invN);
    gather64_lsm<<<gather64Blocks, 256, 0, stream>>>(m3, rowptr, colidx, b3, (float*)d_out, N);
}